// Round 2
// baseline (273.529 us; speedup 1.0000x reference)
//
#include <hip/hip_runtime.h>
#include <hip/hip_bf16.h>
#include <cstddef>

// Problem constants
#define NN 16
#define CC 64
#define TT 300
#define VV 25
#define NHH 4
#define DKHH 16
#define BB (NN * VV)          // 400
#define EPS 1e-5f
#define LOG2E 1.4426950408889634f

// Workspace layout (u32 units)
#define WS_QK    0            // u32[400][64][300]  q|k bf16, paired along o (q pre-scaled 0.25*log2e)
#define WS_V     7680000      // u32[400][64][152]  v bf16, paired along t (t>=300 zero-filled)
#define WS_AH    11571200     // u32[400][64][152]  attnh bf16, paired along t
#define WS_REL   15462400     // u32[41][64][4] key_rel frags (slot = mtile+1, slot0 = zeros)
#define WS_AWF   15472896     // u32[4][2][64][4] attn_w B-frags (pre-scaled by bn scale)
#define WS_AOFF  15474944     // f32[64] fused attn_b+bn offset
#define WS_SCO   15475008     // f32[64] bn scale (for skip path)
#define WS_WFRAG 15475072     // u32[12][2][64][4] qkv_w B-frags (q pre-scaled 0.25*log2e)
#define WS_QB2   15481216     // f32[192] qkv_b (q pre-scaled)
#define WS_SCSH  15481408     // float2[1600] data_bn (sc, sh) per (c, v)

typedef __attribute__((ext_vector_type(8))) short short8;
typedef __attribute__((ext_vector_type(4))) float float4v;

union U8 { short8 v; unsigned int w[4]; };

// f32x2 -> packed bf16x2 (RNE). HW op if available, else manual.
__device__ __forceinline__ unsigned int pk2(float a, float b) {
#if __has_builtin(__builtin_amdgcn_cvt_pk_bf16_f32)
    typedef __attribute__((ext_vector_type(2))) __bf16 bf2;
    union { bf2 v; unsigned u; } c;
    c.v = __builtin_amdgcn_cvt_pk_bf16_f32(a, b);
    return c.u;
#else
    union { float f; unsigned u; } x, y;
    x.f = a; y.f = b;
    unsigned ua = x.u + 0x7FFFu + ((x.u >> 16) & 1u);
    unsigned ub = y.u + 0x7FFFu + ((y.u >> 16) & 1u);
    return (ua >> 16) | (ub & 0xFFFF0000u);
#endif
}

__device__ __forceinline__ float ex2(float x) {
#if __has_builtin(__builtin_amdgcn_exp2f)
    return __builtin_amdgcn_exp2f(x);
#else
    return exp2f(x);
#endif
}

__device__ __forceinline__ float rcpf_(float x) {
#if __has_builtin(__builtin_amdgcn_rcpf)
    return __builtin_amdgcn_rcpf(x);
#else
    return 1.f / x;
#endif
}

// ---------------------------------------------------------------------------
// k_pre: constant tables (shared wfrag/qb2 + scsh restored; per-v wv dropped).
// ---------------------------------------------------------------------------
__global__ __launch_bounds__(256) void k_pre(
    const float* __restrict__ dbn_g, const float* __restrict__ dbn_b,
    const float* __restrict__ dbn_m, const float* __restrict__ dbn_v,
    const float* __restrict__ qkv_w, const float* __restrict__ qkv_b,
    const float* __restrict__ key_rel,
    const float* __restrict__ attn_w, const float* __restrict__ attn_b,
    const float* __restrict__ bn_g, const float* __restrict__ bn_b,
    const float* __restrict__ bn_m, const float* __restrict__ bn_v,
    unsigned* __restrict__ W)
{
    const int jid = blockIdx.x * 256 + threadIdx.x;
    if (jid < 2624) {                      // relfrag: 41 slots x 64 lanes
        const int k = jid >> 6, lane = jid & 63, col = lane & 15, quad = lane >> 4;
        const int mt = k - 1, m = mt * 16 + col;
        const bool ok = (quad < 2) && (mt >= 0) && (m < 2 * TT - 1);
        unsigned w[4];
        #pragma unroll
        for (int j2 = 0; j2 < 4; ++j2) {
            const int c = quad * 8 + 2 * j2;
            const float v0 = ok ? key_rel[m * 16 + c] : 0.f;
            const float v1 = ok ? key_rel[m * 16 + c + 1] : 0.f;
            w[j2] = pk2(v0, v1);
        }
        *(uint4*)&W[WS_REL + k * 256 + lane * 4] = make_uint4(w[0], w[1], w[2], w[3]);
    } else if (jid < 3136) {               // awfrag: 4 otiles x 2 chalf x 64
        const int e = jid - 2624;
        const int ot = e >> 7, ch = (e >> 6) & 1, lane = e & 63;
        const int col = lane & 15, quad = lane >> 4;
        const int o = ot * 16 + col;
        const float sc = bn_g[o] * rsqrtf(bn_v[o] + EPS);
        unsigned w[4];
        #pragma unroll
        for (int j2 = 0; j2 < 4; ++j2) {
            const int c = ch * 32 + quad * 8 + 2 * j2;
            w[j2] = pk2(attn_w[o * 64 + c] * sc, attn_w[o * 64 + c + 1] * sc);
        }
        *(uint4*)&W[WS_AWF + (ot * 2 + ch) * 256 + lane * 4] = make_uint4(w[0], w[1], w[2], w[3]);
    } else if (jid < 3200) {               // aoff
        const int o = jid - 3136;
        const float sc = bn_g[o] * rsqrtf(bn_v[o] + EPS);
        ((float*)(W + WS_AOFF))[o] = attn_b[o] * sc + bn_b[o] - bn_m[o] * sc;
    } else if (jid < 3264) {               // scO
        const int o = jid - 3200;
        ((float*)(W + WS_SCO))[o] = bn_g[o] * rsqrtf(bn_v[o] + EPS);
    } else if (jid < 4800) {               // wfrag: 12 otiles x 2 chalf x 64
        const int e = jid - 3264;
        const int ot = e >> 7, ch = (e >> 6) & 1, lane = e & 63;
        const int col = lane & 15, quad = lane >> 4;
        const int o = ot * 16 + col;
        const float qs = (o < 64) ? 0.25f * LOG2E : 1.f;
        unsigned w[4];
        #pragma unroll
        for (int j2 = 0; j2 < 4; ++j2) {
            const int c = ch * 32 + quad * 8 + 2 * j2;
            w[j2] = pk2(qkv_w[o * 64 + c] * qs, qkv_w[o * 64 + c + 1] * qs);
        }
        *(uint4*)&W[WS_WFRAG + (ot * 2 + ch) * 256 + lane * 4] = make_uint4(w[0], w[1], w[2], w[3]);
    } else if (jid < 4992) {               // qb2
        const int o = jid - 4800;
        ((float*)(W + WS_QB2))[o] = qkv_b[o] * ((o < 64) ? 0.25f * LOG2E : 1.f);
    } else if (jid < 6592) {               // data_bn sc/sh per (c*25+v)
        const int e = jid - 4992;
        const float sc = dbn_g[e] * rsqrtf(dbn_v[e] + EPS);
        const float sh = dbn_b[e] - dbn_m[e] * sc;
        ((float2*)(W + WS_SCSH))[e] = make_float2(sc, sh);
    }
}

// ---------------------------------------------------------------------------
// k_qkv (MFMA): per (t-tile, n), 512 thr. float4 coalesced x loads, data_bn
// applied in staging (scsh fmaf from LDS table); shared weight B-frags loaded
// ONCE per wave.
// ---------------------------------------------------------------------------
__global__ __launch_bounds__(512) void k_qkv(
        const float* __restrict__ x, unsigned* __restrict__ W)
{
    const int tt = blockIdx.x, n = blockIdx.y, t0 = tt * 16;
    const int tid = threadIdx.x;
    const unsigned* wfrag = W + WS_WFRAG;
    const float* qb2 = (const float*)(W + WS_QB2);
    unsigned* qk_p = W + WS_QK;
    unsigned* v_p  = W + WS_V;

    __shared__ unsigned afrag[25 * 516];   // 51.6 KB
    __shared__ float2 sls[1600];           // 12.8 KB data_bn (sc,sh) table in LDS

    for (int i = tid; i < 1600; i += 512)
        sls[i] = ((const float2*)(W + WS_SCSH))[i];
    __syncthreads();

    // stage: 3200 jobs = 32 c-pairs x 100 float4 (contiguous flat = t*25+v)
    for (int i = tid; i < 3200; i += 512) {
        const int f4 = i % 100, cp = i / 100;
        const int c0 = cp * 2;
        float4 xa = make_float4(0.f, 0.f, 0.f, 0.f);
        float4 xb = make_float4(0.f, 0.f, 0.f, 0.f);
        if (tt < 18 || f4 < 75) {          // tail tile: only 300 floats valid
            const float* p = x + (size_t)(n * 64 + c0) * 7500 + tt * 400 + f4 * 4;
            xa = *(const float4*)p;
            xb = *(const float4*)(p + 7500);
        }
        const int ch = cp >> 4, qd = (cp >> 2) & 3, j2 = cp & 3;
        const float ea[4] = {xa.x, xa.y, xa.z, xa.w};
        const float eb[4] = {xb.x, xb.y, xb.z, xb.w};
        #pragma unroll
        for (int e = 0; e < 4; ++e) {
            const int flat = f4 * 4 + e;
            const int tl = (flat * 5243) >> 17;     // flat / 25
            const int v  = flat - 25 * tl;
            const float2 s0 = sls[c0 * 25 + v];
            const float2 s1 = sls[c0 * 25 + 25 + v];
            const float a0 = fmaf(ea[e], s0.x, s0.y);
            const float a1 = fmaf(eb[e], s1.x, s1.y);
            afrag[v * 516 + (ch * 64 + qd * 16 + tl) * 4 + j2] = pk2(a0, a1);
        }
    }
    __syncthreads();

    const int wvv = tid >> 6, lane = tid & 63, col = lane & 15, quad = lane >> 4;
    const int otg = wvv >> 1, vh = wvv & 1;
    const int vlo = 13 * vh, vhi = vh ? 25 : 13;
    const float4v zero4 = {0.f, 0.f, 0.f, 0.f};
    const bool tvalid = (t0 + 4 * quad + 3 < TT);

    U8 bf[3][2]; float qb_l[3];
    #pragma unroll
    for (int i = 0; i < 3; ++i) {
        const int ot = 3 * otg + i;
        #pragma unroll
        for (int ch = 0; ch < 2; ++ch) {
            const uint4 u = *(const uint4*)&wfrag[(ot * 2 + ch) * 256 + lane * 4];
            bf[i][ch].w[0] = u.x; bf[i][ch].w[1] = u.y; bf[i][ch].w[2] = u.z; bf[i][ch].w[3] = u.w;
        }
        qb_l[i] = qb2[ot * 16 + col];
    }

    for (int v = vlo; v < vhi; ++v) {
        const int b = n * 25 + v;
        U8 a0, a1;
        { const uint4 u = *(const uint4*)&afrag[v * 516 + lane * 4];
          a0.w[0] = u.x; a0.w[1] = u.y; a0.w[2] = u.z; a0.w[3] = u.w; }
        { const uint4 u = *(const uint4*)&afrag[v * 516 + 256 + lane * 4];
          a1.w[0] = u.x; a1.w[1] = u.y; a1.w[2] = u.z; a1.w[3] = u.w; }
        #pragma unroll
        for (int i = 0; i < 3; ++i) {
            const int ot = 3 * otg + i;
            float4v acc = __builtin_amdgcn_mfma_f32_16x16x32_bf16(a0.v, bf[i][0].v, zero4, 0, 0, 0);
            acc = __builtin_amdgcn_mfma_f32_16x16x32_bf16(a1.v, bf[i][1].v, acc, 0, 0, 0);
            float val[4];
            #pragma unroll
            for (int r = 0; r < 4; ++r) val[r] = acc[r] + qb_l[i];
            if (ot < 8) {                  // q|k: pair neighbor o lanes
                unsigned pk[4];
                #pragma unroll
                for (int r = 0; r < 4; ++r) {
                    const float p = __shfl_xor(val[r], 1);
                    pk[r] = pk2(val[r], p);
                }
                if (((col & 1) == 0) && tvalid) {
                    const int op = ot * 8 + (col >> 1);
                    *(uint4*)&qk_p[(size_t)(b * 64 + op) * TT + t0 + 4 * quad] =
                        make_uint4(pk[0], pk[1], pk[2], pk[3]);
                }
            } else {                       // v: pair along t; zero-fill t>=300
                const int d = (ot - 8) * 16 + col;
                uint2 u;
                if (tvalid) { u.x = pk2(val[0], val[1]); u.y = pk2(val[2], val[3]); }
                else        { u.x = 0u; u.y = 0u; }
                *(uint2*)&v_p[(size_t)(b * 64 + d) * 152 + 8 * tt + 2 * quad] = u;
            }
        }
    }
}

// ---------------------------------------------------------------------------
// attn tile engine: NT t-tiles processed in lockstep per wave. K/V fragments
// are SHARED across the tiles of a pair (they don't depend on t), so per
// chunk we pay 3 shared LDS b128 reads and run NT independent
// QK->exp->pk2->PV chains -- 2x ILP per wave to hide MFMA/trans/LDS latency.
// ---------------------------------------------------------------------------
template<int NT>
__device__ __forceinline__ void attn_tiles(
    int b, int h, int tta, int ttb,
    const unsigned* __restrict__ qk_p,
    const unsigned* __restrict__ relfrag,
    const unsigned* kbuf, const unsigned* vbuf,
    float* relw0, float* relw1,
    unsigned* __restrict__ ah_p,
    int lane, int col, int quad)
{
    const float4v zero4 = {0.f, 0.f, 0.f, 0.f};
    U8 onef;
    onef.w[0] = onef.w[1] = onef.w[2] = onef.w[3] = 0x3F803F80u;

    int tts[2]; tts[0] = tta; tts[1] = ttb;
    float* relw[2]; relw[0] = relw0; relw[1] = relw1;

    // ---- Q B-frags (cols = t) ----
    U8 qf[NT];
    #pragma unroll
    for (int j = 0; j < NT; ++j) {
        const int t0 = tts[j] * 16;
        if (quad < 2) {
            int t = t0 + col; if (t > TT - 1) t = TT - 1;
            const size_t rb = (size_t)(b * 64 + h * 8 + quad * 4) * TT + t;
            qf[j].w[0] = qk_p[rb];
            qf[j].w[1] = qk_p[rb + TT];
            qf[j].w[2] = qk_p[rb + 2 * TT];
            qf[j].w[3] = qk_p[rb + 3 * TT];
        } else {
            qf[j].w[0] = qf[j].w[1] = qf[j].w[2] = qf[j].w[3] = 0u;
        }
    }

    auto rel_ld = [&](int mt) -> uint4 {
        return *(const uint4*)&relfrag[(mt + 1) * 256 + lane * 4];
    };
    auto rel_do = [&](int j, int mt, uint4 u) {
        U8 kr; kr.w[0] = u.x; kr.w[1] = u.y; kr.w[2] = u.z; kr.w[3] = u.w;
        const float4v rc = __builtin_amdgcn_mfma_f32_16x16x32_bf16(
                               kr.v, qf[j].v, zero4, 0, 0, 0);
        const float4 s4 = make_float4(rc[0], rc[1], rc[2], rc[3]);
        *(float4*)&relw[j][col * 68 + ((mt & 3) * 16 + quad * 4)] = s4;
        if (((mt & 3) == 0) && (quad == 0))
            *(float4*)&relw[j][col * 68 + 64] = s4;
    };

    uint4 ru0[NT], ru1[NT];
    #pragma unroll
    for (int j = 0; j < NT; ++j) {
        const int tt = tts[j];
        #pragma unroll
        for (int i = 0; i < 4; ++i) rel_do(j, 17 - tt + i, rel_ld(17 - tt + i));
        ru0[j] = rel_ld(21 - tt); ru1[j] = rel_ld(22 - tt);
    }

    float4v accPV[NT], accS[NT];
    int mbb[NT];
    #pragma unroll
    for (int j = 0; j < NT; ++j) {
        accPV[j] = zero4; accS[j] = zero4;
        mbb[j] = 4 * quad - tts[j] * 16 - col + (TT - 1);
    }

    #pragma unroll 1
    for (int c = 0; c < 9; ++c) {       // chunks of 2 s-tiles: s 0..287
        U8 kf0, kf1;
        if (quad < 2) {
            const uint4 u0 = *(const uint4*)&kbuf[((2 * c) * 32 + quad * 16 + col) * 4];
            const uint4 u1 = *(const uint4*)&kbuf[((2 * c + 1) * 32 + quad * 16 + col) * 4];
            kf0.w[0] = u0.x; kf0.w[1] = u0.y; kf0.w[2] = u0.z; kf0.w[3] = u0.w;
            kf1.w[0] = u1.x; kf1.w[1] = u1.y; kf1.w[2] = u1.z; kf1.w[3] = u1.w;
        } else {
            kf0.w[0] = kf0.w[1] = kf0.w[2] = kf0.w[3] = 0u;
            kf1.w[0] = kf1.w[1] = kf1.w[2] = kf1.w[3] = 0u;
        }
        const short8 vf = *(const short8*)&vbuf[(c * 64 + lane) * 4];

        #pragma unroll
        for (int j = 0; j < NT; ++j) {
            const int mb0 = 32 * c + mbb[j];
            const float* rp0 = &relw[j][col * 68 + (mb0 & 63)];
            const float* rp1 = &relw[j][col * 68 + ((mb0 + 16) & 63)];
            const float4v rc0 = { rp0[0], rp0[1], rp0[2], rp0[3] };
            const float4v rc1 = { rp1[0], rp1[1], rp1[2], rp1[3] };
            const float4v qk0 = __builtin_amdgcn_mfma_f32_16x16x32_bf16(kf0.v, qf[j].v, rc0, 0, 0, 0);
            const float4v qk1 = __builtin_amdgcn_mfma_f32_16x16x32_bf16(kf1.v, qf[j].v, rc1, 0, 0, 0);

            const float e0 = ex2(qk0[0]);
            const float e1 = ex2(qk0[1]);
            const float e2 = ex2(qk0[2]);
            const float e3 = ex2(qk0[3]);
            const float e4 = ex2(qk1[0]);
            const float e5 = ex2(qk1[1]);
            const float e6 = ex2(qk1[2]);
            const float e7 = ex2(qk1[3]);

            U8 pf;
            pf.w[0] = pk2(e0, e1);
            pf.w[1] = pk2(e2, e3);
            pf.w[2] = pk2(e4, e5);
            pf.w[3] = pk2(e6, e7);
            accPV[j] = __builtin_amdgcn_mfma_f32_16x16x32_bf16(pf.v, vf, accPV[j], 0, 0, 0);
            accS[j]  = __builtin_amdgcn_mfma_f32_16x16x32_bf16(pf.v, onef.v, accS[j], 0, 0, 0);

            rel_do(j, 2 * c + 21 - tts[j], ru0[j]);
            rel_do(j, 2 * c + 22 - tts[j], ru1[j]);
            if (c < 8) {
                ru0[j] = rel_ld(2 * c + 23 - tts[j]);
                ru1[j] = rel_ld(2 * c + 24 - tts[j]);
            }
        }
    }

    // ---- tail chunk 9: stile 18 only (s 288..303; s>=300 masked) ----
    {
        U8 kf0;
        if (quad < 2) {
            const uint4 u0 = *(const uint4*)&kbuf[(18 * 32 + quad * 16 + col) * 4];
            kf0.w[0] = u0.x; kf0.w[1] = u0.y; kf0.w[2] = u0.z; kf0.w[3] = u0.w;
        } else {
            kf0.w[0] = kf0.w[1] = kf0.w[2] = kf0.w[3] = 0u;
        }
        const short8 vf = *(const short8*)&vbuf[(9 * 64 + lane) * 4];
        #pragma unroll
        for (int j = 0; j < NT; ++j) {
            const int mb0 = 288 + mbb[j];
            const float* rp0 = &relw[j][col * 68 + (mb0 & 63)];
            const float4v rc0 = { rp0[0], rp0[1], rp0[2], rp0[3] };
            const float4v qk0 = __builtin_amdgcn_mfma_f32_16x16x32_bf16(kf0.v, qf[j].v, rc0, 0, 0, 0);
            float e0 = ex2(qk0[0]);
            float e1 = ex2(qk0[1]);
            float e2 = ex2(qk0[2]);
            float e3 = ex2(qk0[3]);
            if (quad == 3) { e0 = e1 = e2 = e3 = 0.f; }
            U8 pf;
            pf.w[0] = pk2(e0, e1);
            pf.w[1] = pk2(e2, e3);
            pf.w[2] = 0u;
            pf.w[3] = 0u;
            accPV[j] = __builtin_amdgcn_mfma_f32_16x16x32_bf16(pf.v, vf, accPV[j], 0, 0, 0);
            accS[j]  = __builtin_amdgcn_mfma_f32_16x16x32_bf16(pf.v, onef.v, accS[j], 0, 0, 0);
        }
    }

    // ---- finalize: accS holds per-lane row sums (t = 4*quad+r, same mapping
    // as accPV). Normalize (rcp), bf16 t-paired store. ----
    #pragma unroll
    for (int j = 0; j < NT; ++j) {
        const int t0 = tts[j] * 16;
        if (t0 + 4 * quad + 3 < TT) {
            uint2 u;
            u.x = pk2(accPV[j][0] * rcpf_(accS[j][0]), accPV[j][1] * rcpf_(accS[j][1]));
            u.y = pk2(accPV[j][2] * rcpf_(accS[j][2]), accPV[j][3] * rcpf_(accS[j][3]));
            *(uint2*)&ah_p[(size_t)(b * 64 + h * 16 + col) * 152 + 8 * tts[j] + 2 * quad] = u;
        }
    }
}

// ---------------------------------------------------------------------------
// k_attn: per (b, h, t-half). Waves process t-tile PAIRS (shared K/V frags,
// 2 independent softmax chains) then leftover singles.
// ---------------------------------------------------------------------------
__global__ __launch_bounds__(256) void k_attn(unsigned* __restrict__ W)
{
    const int bh = blockIdx.x;             // 0..1599
    const int half = blockIdx.y;           // t-range half
    const int b = bh >> 2, h = bh & 3;
    const int tid  = threadIdx.x;
    const int wave = tid >> 6, lane = tid & 63;
    const int col  = lane & 15, quad = lane >> 4;

    const unsigned* qk_p = W + WS_QK;
    const unsigned* v_p  = W + WS_V;
    unsigned* ah_p = W + WS_AH;
    const unsigned* relfrag = W + WS_REL;

    __shared__ unsigned kbuf[19 * 32 * 4];   // 9.7 KB
    __shared__ unsigned vbuf[10 * 64 * 4];   // 10.2 KB (s-permuted)
    __shared__ float relbuf[4][2][16 * 68];  // per-(wave, pair-slot) rel ring, 34.8 KB

    for (int p = tid; p < 2432; p += 256) {
        const int c = p & 15, j2 = (p >> 4) & 3, qh = (p >> 6) & 1, st = p >> 7;
        kbuf[(st * 32 + qh * 16 + c) * 4 + j2] =
            qk_p[(size_t)(b * 64 + 32 + h * 8 + qh * 4 + j2) * TT + st * 16 + c];
    }
    // V staging with k<->s permutation: quad q of the PV A/B frag owns
    // s-pairs {2q, 2q+1, 8+2q, 8+2q+1} within each 32-s chunk.
    for (int p = tid; p < 640; p += 256) {
        const int tq = p % 40, d = p / 40;
        const int off = (tq * 4 <= 148) ? tq * 4 : 144;  // clamp (slots unused)
        const uint4 u = *(const uint4*)&v_p[(size_t)(b * 64 + h * 16 + d) * 152 + off];
        const int c = tq >> 2;
        const int l0 = (tq & 3) * 4;
        const unsigned uu[4] = {u.x, u.y, u.z, u.w};
        #pragma unroll
        for (int j = 0; j < 4; ++j) {
            const int local = l0 + j;
            const int q  = (local < 8) ? (local >> 1) : ((local - 8) >> 1);
            const int j2 = (local < 8) ? (local & 1) : (2 + (local & 1));
            vbuf[(c * 64 + q * 16 + d) * 4 + j2] = uu[j];
        }
    }
    __syncthreads();

    const int ttlo = half ? 10 : 0;

    // pair phase: waves 0..3 -> tiles (ttlo+2w, ttlo+2w+1)
    {
        const int p0 = ttlo + 2 * wave;
        attn_tiles<2>(b, h, p0, p0 + 1, qk_p, relfrag, kbuf, vbuf,
                      &relbuf[wave][0][0], &relbuf[wave][1][0],
                      ah_p, lane, col, quad);
    }
    // leftover singles: half0 -> tiles 8,9 on waves 0,1; half1 -> tile 18 on wave 0
    if (half == 0) {
        if (wave < 2)
            attn_tiles<1>(b, h, 8 + wave, 8 + wave, qk_p, relfrag, kbuf, vbuf,
                          &relbuf[wave][0][0], &relbuf[wave][0][0],
                          ah_p, lane, col, quad);
    } else {
        if (wave == 0)
            attn_tiles<1>(b, h, 18, 18, qk_p, relfrag, kbuf, vbuf,
                          &relbuf[0][0][0], &relbuf[0][0][0],
                          ah_p, lane, col, quad);
    }
}

// ---------------------------------------------------------------------------
// k_out (MFMA): per (t-tile, n, t-quarter), 512 thr (waves = otile x t-half).
// x and out through LDS flat buffers (float4-coalesced global traffic).
// ---------------------------------------------------------------------------
__global__ __launch_bounds__(512) void k_out(
        const float* __restrict__ x, const unsigned* __restrict__ W,
        float* __restrict__ out)
{
    const int tt = blockIdx.x, n = blockIdx.y, tq = blockIdx.z;
    if (tt == 18 && tq == 3) return;
    const int t0q = tt * 16 + tq * 4;
    const int tid = threadIdx.x;
    const unsigned* ah_p = W + WS_AH;
    const unsigned* awfrag = W + WS_AWF;
    const float* aoff = (const float*)(W + WS_AOFF);
    const float* scO  = (const float*)(W + WS_SCO);

    __shared__ unsigned fbuf[4 * 1024];    // 16 KB (ah A-frags)
    __shared__ float obuf[6400];           // 25.6 KB (x tile, then out tile)

    // stage x tile (64 o x 4 t x 25 v) via flat float4 (fully coalesced)
    for (int j = tid; j < 1600; j += 512) {
        const int o = j / 25, f4 = j - 25 * o;
        const float4 xv = *(const float4*)(x + (size_t)(n * 64 + o) * 7500 + t0q * 25 + f4 * 4);
        *(float4*)&obuf[o * 100 + f4 * 4] = xv;
    }
    // stage ah A-frags
    for (int i = tid; i < 1600; i += 512) {
        const int tp2 = i & 1, pc = (i >> 1) & 31, v = i >> 6;
        const int b = n * 25 + v;
        const size_t r0 = (size_t)(b * 64 + 2 * pc) * 152 + tt * 8 + tq * 2 + tp2;
        const unsigned A = ah_p[r0], Bv = ah_p[r0 + 152];
        const unsigned ue = (A & 0xFFFFu) | (Bv << 16);
        const unsigned uo = (A >> 16) | (Bv & 0xFFFF0000u);
        const int vt = v >> 4, cv = v & 15, ch = pc >> 4, qd = (pc >> 2) & 3, j2 = pc & 3;
        const int xi = (vt * 2 + ch) * 256 + (qd * 16 + (cv ^ qd)) * 4 + j2;
        const int tl = 2 * tp2;
        fbuf[tl * 1024 + ((xi + 12 * tl) & 1023)]             = ue;
        fbuf[(tl + 1) * 1024 + ((xi + 12 * (tl + 1)) & 1023)] = uo;
    }
    __syncthreads();

    const int wv = tid >> 6, lane = tid & 63, col = lane & 15, quad = lane >> 4;
    const int ow = wv & 3, th = wv >> 2;
    const int o = ow * 16 + col;
    const float4v zero4 = {0.f, 0.f, 0.f, 0.f};

    U8 awf0, awf1;
    { const uint4 u = *(const uint4*)&awfrag[(ow * 2 + 0) * 256 + lane * 4];
      awf0.w[0] = u.x; awf0.w[1] = u.y; awf0.w[2] = u.z; awf0.w[3] = u.w; }
    { const uint4 u = *(const uint4*)&awfrag[(ow * 2 + 1) * 256 + lane * 4];
      awf1.w[0] = u.x; awf1.w[1] = u.y; awf1.w[2] = u.z; awf1.w[3] = u.w; }
    const float aoff_l = aoff[o], sc_l = scO[o];

    for (int tl = 2 * th; tl < 2 * th + 2; ++tl) {
        #pragma unroll
        for (int vt = 0; vt < 2; ++vt) {
            U8 a0, a1;
            { const int xb = (vt * 2 + 0) * 256 + (quad * 16 + (col ^ quad)) * 4;
              const uint4 u = *(const uint4*)&fbuf[tl * 1024 + ((xb + 12 * tl) & 1023)];
              a0.w[0] = u.x; a0.w[1] = u.y; a0.w[2] = u.z; a0.w[3] = u.w; }
            { const int xb = (vt * 2 + 1) * 256 + (quad * 16 + (col ^ quad)) * 4;
              const uint4 u = *(const uint4*)&fbuf[tl * 1024 + ((xb + 12 * tl) & 1023)];
              a1.w[0] = u.x; a1.w[1] = u.y; a1.w[2] = u.z; a1.w[3] = u.w; }
            float4v acc = __builtin_amdgcn_mfma_f32_16x16x32_bf16(a0.v, awf0.v, zero4, 0, 0, 0);
            acc = __builtin_amdgcn_mfma_f32_16x16x32_bf16(a1.v, awf1.v, acc, 0, 0, 0);
            #pragma unroll
            for (int r = 0; r < 4; ++r) {
                const int v = vt * 16 + 4 * quad + r;
                if (v < 25) {
                    const int oi = o * 100 + tl * 25 + v;
                    obuf[oi] = fmaxf(fmaf(obuf[oi], sc_l, acc[r] + aoff_l), 0.f);
                }
            }
        }
    }
    __syncthreads();

    // flush out tile via flat float4 (fully coalesced)
    for (int j = tid; j < 1600; j += 512) {
        const int o2 = j / 25, f4 = j - 25 * o2;
        *(float4*)(out + (size_t)(n * 64 + o2) * 7500 + t0q * 25 + f4 * 4) =
            *(const float4*)&obuf[o2 * 100 + f4 * 4];
    }
}

// ---------------------------------------------------------------------------
extern "C" void kernel_launch(void* const* d_in, const int* in_sizes, int n_in,
                              void* d_out, int out_size, void* d_ws, size_t ws_size,
                              hipStream_t stream)
{
    const float* x       = (const float*)d_in[0];
    const float* dbn_g   = (const float*)d_in[1];
    const float* dbn_b   = (const float*)d_in[2];
    const float* dbn_m   = (const float*)d_in[3];
    const float* dbn_v   = (const float*)d_in[4];
    const float* qkv_w   = (const float*)d_in[5];
    const float* qkv_b   = (const float*)d_in[6];
    const float* key_rel = (const float*)d_in[7];
    const float* attn_w  = (const float*)d_in[8];
    const float* attn_b  = (const float*)d_in[9];
    const float* bn_g    = (const float*)d_in[10];
    const float* bn_b    = (const float*)d_in[11];
    const float* bn_m    = (const float*)d_in[12];
    const float* bn_v    = (const float*)d_in[13];
    float* out = (float*)d_out;
    unsigned* W = (unsigned*)d_ws;

    k_pre<<<26, 256, 0, stream>>>(dbn_g, dbn_b, dbn_m, dbn_v, qkv_w, qkv_b,
                                  key_rel, attn_w, attn_b, bn_g, bn_b, bn_m,
                                  bn_v, W);
    k_qkv<<<dim3(19, 16), 512, 0, stream>>>(x, W);
    k_attn<<<dim3(1600, 2), 256, 0, stream>>>(W);
    k_out<<<dim3(19, 16, 4), 512, 0, stream>>>(x, W, out);
}

// Round 3
// 257.990 us; speedup vs baseline: 1.0602x; 1.0602x over previous
//
#include <hip/hip_runtime.h>
#include <hip/hip_bf16.h>
#include <cstddef>

// Problem constants
#define NN 16
#define CC 64
#define TT 300
#define VV 25
#define NHH 4
#define DKHH 16
#define BB (NN * VV)          // 400
#define EPS 1e-5f
#define LOG2E 1.4426950408889634f

// Workspace layout (u32 units)
#define WS_QK    0            // u32[400][32][300]  q bf16, paired along o (pre-scaled 0.25*log2e)
#define WS_KP    3840000      // u32[400][4][19][2][16][4]  K frags (st, qh, c, j2) = 2432/(b,h)
#define WS_VP    7731200      // u32[400][4][10][4][16][4]  V frags (c, q, d, j2) = 2560/(b,h)
#define WS_AH    11827200     // u32[400][64][152]  attnh bf16, paired along t
#define WS_REL   15718400     // u32[41][64][4] key_rel frags (slot = mtile+1, slot0 = zeros)
#define WS_AWF   15728896     // u32[4][2][64][4] attn_w B-frags (pre-scaled by bn scale)
#define WS_AOFF  15730944     // f32[64] fused attn_b+bn offset
#define WS_SCO   15731008     // f32[64] bn scale (for skip path)
#define WS_WFRAG 15731072     // u32[12][2][64][4] qkv_w B-frags (q pre-scaled 0.25*log2e)
#define WS_QB2   15737216     // f32[192] qkv_b (q pre-scaled)
#define WS_SCSH  15737408     // float2[1600] data_bn (sc, sh) per (c, v)

typedef __attribute__((ext_vector_type(8))) short short8;
typedef __attribute__((ext_vector_type(4))) float float4v;

union U8 { short8 v; unsigned int w[4]; };

// f32x2 -> packed bf16x2 (RNE). HW op if available, else manual.
__device__ __forceinline__ unsigned int pk2(float a, float b) {
#if __has_builtin(__builtin_amdgcn_cvt_pk_bf16_f32)
    typedef __attribute__((ext_vector_type(2))) __bf16 bf2;
    union { bf2 v; unsigned u; } c;
    c.v = __builtin_amdgcn_cvt_pk_bf16_f32(a, b);
    return c.u;
#else
    union { float f; unsigned u; } x, y;
    x.f = a; y.f = b;
    unsigned ua = x.u + 0x7FFFu + ((x.u >> 16) & 1u);
    unsigned ub = y.u + 0x7FFFu + ((y.u >> 16) & 1u);
    return (ua >> 16) | (ub & 0xFFFF0000u);
#endif
}

__device__ __forceinline__ float ex2(float x) {
#if __has_builtin(__builtin_amdgcn_exp2f)
    return __builtin_amdgcn_exp2f(x);
#else
    return exp2f(x);
#endif
}

__device__ __forceinline__ float rcpf_(float x) {
#if __has_builtin(__builtin_amdgcn_rcpf)
    return __builtin_amdgcn_rcpf(x);
#else
    return 1.f / x;
#endif
}

// ---------------------------------------------------------------------------
// k_pre: constant tables.
// ---------------------------------------------------------------------------
__global__ __launch_bounds__(256) void k_pre(
    const float* __restrict__ dbn_g, const float* __restrict__ dbn_b,
    const float* __restrict__ dbn_m, const float* __restrict__ dbn_v,
    const float* __restrict__ qkv_w, const float* __restrict__ qkv_b,
    const float* __restrict__ key_rel,
    const float* __restrict__ attn_w, const float* __restrict__ attn_b,
    const float* __restrict__ bn_g, const float* __restrict__ bn_b,
    const float* __restrict__ bn_m, const float* __restrict__ bn_v,
    unsigned* __restrict__ W)
{
    const int jid = blockIdx.x * 256 + threadIdx.x;
    if (jid < 2624) {                      // relfrag: 41 slots x 64 lanes
        const int k = jid >> 6, lane = jid & 63, col = lane & 15, quad = lane >> 4;
        const int mt = k - 1, m = mt * 16 + col;
        const bool ok = (quad < 2) && (mt >= 0) && (m < 2 * TT - 1);
        unsigned w[4];
        #pragma unroll
        for (int j2 = 0; j2 < 4; ++j2) {
            const int c = quad * 8 + 2 * j2;
            const float v0 = ok ? key_rel[m * 16 + c] : 0.f;
            const float v1 = ok ? key_rel[m * 16 + c + 1] : 0.f;
            w[j2] = pk2(v0, v1);
        }
        *(uint4*)&W[WS_REL + k * 256 + lane * 4] = make_uint4(w[0], w[1], w[2], w[3]);
    } else if (jid < 3136) {               // awfrag: 4 otiles x 2 chalf x 64
        const int e = jid - 2624;
        const int ot = e >> 7, ch = (e >> 6) & 1, lane = e & 63;
        const int col = lane & 15, quad = lane >> 4;
        const int o = ot * 16 + col;
        const float sc = bn_g[o] * rsqrtf(bn_v[o] + EPS);
        unsigned w[4];
        #pragma unroll
        for (int j2 = 0; j2 < 4; ++j2) {
            const int c = ch * 32 + quad * 8 + 2 * j2;
            w[j2] = pk2(attn_w[o * 64 + c] * sc, attn_w[o * 64 + c + 1] * sc);
        }
        *(uint4*)&W[WS_AWF + (ot * 2 + ch) * 256 + lane * 4] = make_uint4(w[0], w[1], w[2], w[3]);
    } else if (jid < 3200) {               // aoff
        const int o = jid - 3136;
        const float sc = bn_g[o] * rsqrtf(bn_v[o] + EPS);
        ((float*)(W + WS_AOFF))[o] = attn_b[o] * sc + bn_b[o] - bn_m[o] * sc;
    } else if (jid < 3264) {               // scO
        const int o = jid - 3200;
        ((float*)(W + WS_SCO))[o] = bn_g[o] * rsqrtf(bn_v[o] + EPS);
    } else if (jid < 4800) {               // wfrag: 12 otiles x 2 chalf x 64
        const int e = jid - 3264;
        const int ot = e >> 7, ch = (e >> 6) & 1, lane = e & 63;
        const int col = lane & 15, quad = lane >> 4;
        const int o = ot * 16 + col;
        const float qs = (o < 64) ? 0.25f * LOG2E : 1.f;
        unsigned w[4];
        #pragma unroll
        for (int j2 = 0; j2 < 4; ++j2) {
            const int c = ch * 32 + quad * 8 + 2 * j2;
            w[j2] = pk2(qkv_w[o * 64 + c] * qs, qkv_w[o * 64 + c + 1] * qs);
        }
        *(uint4*)&W[WS_WFRAG + (ot * 2 + ch) * 256 + lane * 4] = make_uint4(w[0], w[1], w[2], w[3]);
    } else if (jid < 4992) {               // qb2
        const int o = jid - 4800;
        ((float*)(W + WS_QB2))[o] = qkv_b[o] * ((o < 64) ? 0.25f * LOG2E : 1.f);
    } else if (jid < 6592) {               // data_bn sc/sh per (c*25+v)
        const int e = jid - 4992;
        const float sc = dbn_g[e] * rsqrtf(dbn_v[e] + EPS);
        const float sh = dbn_b[e] - dbn_m[e] * sc;
        ((float2*)(W + WS_SCSH))[e] = make_float2(sc, sh);
    }
}

// ---------------------------------------------------------------------------
// k_qkv (MFMA): per (t-tile, n), 512 thr. Q stored t-major (for Q B-frag
// reads); K and V stored DIRECTLY in k_attn's fragment layouts (kperm/vperm)
// so k_attn needs no LDS staging at all. Invalid-t slots zero-filled.
// ---------------------------------------------------------------------------
__global__ __launch_bounds__(512) void k_qkv(
        const float* __restrict__ x, unsigned* __restrict__ W)
{
    const int tt = blockIdx.x, n = blockIdx.y, t0 = tt * 16;
    const int tid = threadIdx.x;
    const unsigned* wfrag = W + WS_WFRAG;
    const float* qb2 = (const float*)(W + WS_QB2);
    unsigned* q_p = W + WS_QK;
    unsigned* k_p = W + WS_KP;
    unsigned* v_p = W + WS_VP;

    __shared__ unsigned afrag[25 * 516];   // 51.6 KB
    __shared__ float2 sls[1600];           // 12.8 KB data_bn (sc,sh) table

    for (int i = tid; i < 1600; i += 512)
        sls[i] = ((const float2*)(W + WS_SCSH))[i];
    __syncthreads();

    // stage: 3200 jobs = 32 c-pairs x 100 float4 (contiguous flat = t*25+v)
    for (int i = tid; i < 3200; i += 512) {
        const int f4 = i % 100, cp = i / 100;
        const int c0 = cp * 2;
        float4 xa = make_float4(0.f, 0.f, 0.f, 0.f);
        float4 xb = make_float4(0.f, 0.f, 0.f, 0.f);
        if (tt < 18 || f4 < 75) {          // tail tile: only 300 floats valid
            const float* p = x + (size_t)(n * 64 + c0) * 7500 + tt * 400 + f4 * 4;
            xa = *(const float4*)p;
            xb = *(const float4*)(p + 7500);
        }
        const int ch = cp >> 4, qd = (cp >> 2) & 3, j2 = cp & 3;
        const float ea[4] = {xa.x, xa.y, xa.z, xa.w};
        const float eb[4] = {xb.x, xb.y, xb.z, xb.w};
        #pragma unroll
        for (int e = 0; e < 4; ++e) {
            const int flat = f4 * 4 + e;
            const int tl = (flat * 5243) >> 17;     // flat / 25
            const int v  = flat - 25 * tl;
            const float2 s0 = sls[c0 * 25 + v];
            const float2 s1 = sls[c0 * 25 + 25 + v];
            const float a0 = fmaf(ea[e], s0.x, s0.y);
            const float a1 = fmaf(eb[e], s1.x, s1.y);
            afrag[v * 516 + (ch * 64 + qd * 16 + tl) * 4 + j2] = pk2(a0, a1);
        }
    }
    __syncthreads();

    const int wvv = tid >> 6, lane = tid & 63, col = lane & 15, quad = lane >> 4;
    const int otg = wvv >> 1, vh = wvv & 1;
    const int vlo = 13 * vh, vhi = vh ? 25 : 13;
    const float4v zero4 = {0.f, 0.f, 0.f, 0.f};
    const bool tvalid = (t0 + 4 * quad + 3 < TT);

    U8 bf[3][2]; float qb_l[3];
    #pragma unroll
    for (int i = 0; i < 3; ++i) {
        const int ot = 3 * otg + i;
        #pragma unroll
        for (int ch = 0; ch < 2; ++ch) {
            const uint4 u = *(const uint4*)&wfrag[(ot * 2 + ch) * 256 + lane * 4];
            bf[i][ch].w[0] = u.x; bf[i][ch].w[1] = u.y; bf[i][ch].w[2] = u.z; bf[i][ch].w[3] = u.w;
        }
        qb_l[i] = qb2[ot * 16 + col];
    }

    for (int v = vlo; v < vhi; ++v) {
        const int b = n * 25 + v;
        U8 a0, a1;
        { const uint4 u = *(const uint4*)&afrag[v * 516 + lane * 4];
          a0.w[0] = u.x; a0.w[1] = u.y; a0.w[2] = u.z; a0.w[3] = u.w; }
        { const uint4 u = *(const uint4*)&afrag[v * 516 + 256 + lane * 4];
          a1.w[0] = u.x; a1.w[1] = u.y; a1.w[2] = u.z; a1.w[3] = u.w; }
        #pragma unroll
        for (int i = 0; i < 3; ++i) {
            const int ot = 3 * otg + i;
            float4v acc = __builtin_amdgcn_mfma_f32_16x16x32_bf16(a0.v, bf[i][0].v, zero4, 0, 0, 0);
            acc = __builtin_amdgcn_mfma_f32_16x16x32_bf16(a1.v, bf[i][1].v, acc, 0, 0, 0);
            float val[4];
            #pragma unroll
            for (int r = 0; r < 4; ++r) val[r] = acc[r] + qb_l[i];
            if (ot < 8) {                  // q|k: pair neighbor o lanes
                unsigned pk[4];
                #pragma unroll
                for (int r = 0; r < 4; ++r) {
                    const float p = __shfl_xor(val[r], 1);
                    pk[r] = pk2(val[r], p);
                }
                if (ot < 4) {              // q -> t-major q_p (ops 0..31)
                    if (((col & 1) == 0) && tvalid) {
                        const int op = ot * 8 + (col >> 1);
                        *(uint4*)&q_p[(size_t)(b * 32 + op) * TT + t0 + 4 * quad] =
                            make_uint4(pk[0], pk[1], pk[2], pk[3]);
                    }
                } else {                   // k -> kperm frag layout, zero-fill tail
                    if ((col & 1) == 0) {
                        const int kh = ot - 4, cp2 = col >> 1;
                        const int qh = cp2 >> 2, j2 = cp2 & 3;
                        unsigned* dst = k_p + (size_t)(b * 4 + kh) * 2432
                                        + tt * 128 + qh * 64 + quad * 16 + j2;
                        #pragma unroll
                        for (int r = 0; r < 4; ++r)
                            dst[4 * r] = tvalid ? pk[r] : 0u;
                    }
                }
            } else {                       // v -> vperm frag layout (s-permuted)
                const int hh = ot - 8, dd = col;
                unsigned* vdst = v_p + (size_t)(b * 4 + hh) * 2560;
                const unsigned ux = tvalid ? pk2(val[0], val[1]) : 0u;
                const unsigned uy = tvalid ? pk2(val[2], val[3]) : 0u;
                const int tp0 = 8 * tt + 2 * quad;
                #pragma unroll
                for (int e = 0; e < 2; ++e) {
                    const int tp = tp0 + e;
                    const int c9 = tp >> 4, l = tp & 15;
                    const int qs = (l < 8) ? (l >> 1) : ((l - 8) >> 1);
                    const int js = (l < 8) ? (l & 1) : (2 + (l & 1));
                    vdst[(c9 * 64 + qs * 16 + dd) * 4 + js] = e ? uy : ux;
                }
                if (tt == 18 && quad == 3) {   // zero-fill tp 152..159 (s 304..319)
                    #pragma unroll
                    for (int q = 0; q < 4; ++q) {
                        vdst[(9 * 64 + q * 16 + dd) * 4 + 2] = 0u;
                        vdst[(9 * 64 + q * 16 + dd) * 4 + 3] = 0u;
                    }
                }
            }
        }
    }
}

// ---------------------------------------------------------------------------
// k_attn: one 512-thr block per (b,h); 8 independent waves, t-tiles strided
// by 8. NO LDS staging, NO syncthreads: K/V fragments read straight from
// kperm/vperm (coalesced, L2-resident 20KB/(b,h)). LDS = per-wave rel ring
// only (34.8 KB) -> 4 blocks/CU = 32 waves/CU.
// ---------------------------------------------------------------------------
__global__ __launch_bounds__(512, 8) void k_attn(unsigned* __restrict__ W)
{
    const int bh = blockIdx.x;             // 0..1599
    const int b = bh >> 2, h = bh & 3;
    const int tid  = threadIdx.x;
    const int wave = tid >> 6, lane = tid & 63;
    const int col  = lane & 15, quad = lane >> 4;

    const unsigned* q_p = W + WS_QK;
    const unsigned* kp  = W + WS_KP + (size_t)(b * 4 + h) * 2432;
    const unsigned* vp  = W + WS_VP + (size_t)(b * 4 + h) * 2560;
    unsigned* ah_p = W + WS_AH;
    const unsigned* relfrag = W + WS_REL;

    __shared__ float relbuf[8][16 * 68];   // per-wave rel ring, 34.8 KB

    float* relw = &relbuf[wave][0];
    const float4v zero4 = {0.f, 0.f, 0.f, 0.f};
    U8 onef;
    onef.w[0] = onef.w[1] = onef.w[2] = onef.w[3] = 0x3F803F80u;

    for (int tt = wave; tt < 19; tt += 8) {
        const int t0 = tt * 16;

        // ---- Q B-frag (cols = t) ----
        U8 qf;
        if (quad < 2) {
            int t = t0 + col; if (t > TT - 1) t = TT - 1;
            const size_t rb = (size_t)(b * 32 + h * 8 + quad * 4) * TT + t;
            qf.w[0] = q_p[rb];
            qf.w[1] = q_p[rb + TT];
            qf.w[2] = q_p[rb + 2 * TT];
            qf.w[3] = q_p[rb + 3 * TT];
        } else {
            qf.w[0] = qf.w[1] = qf.w[2] = qf.w[3] = 0u;
        }

        auto rel_ld = [&](int mt) -> uint4 {
            return *(const uint4*)&relfrag[(mt + 1) * 256 + lane * 4];
        };
        auto rel_do = [&](int mt, uint4 u) {
            U8 kr; kr.w[0] = u.x; kr.w[1] = u.y; kr.w[2] = u.z; kr.w[3] = u.w;
            const float4v rc = __builtin_amdgcn_mfma_f32_16x16x32_bf16(
                                   kr.v, qf.v, zero4, 0, 0, 0);
            const float4 s4 = make_float4(rc[0], rc[1], rc[2], rc[3]);
            *(float4*)&relw[col * 68 + ((mt & 3) * 16 + quad * 4)] = s4;
            if (((mt & 3) == 0) && (quad == 0))
                *(float4*)&relw[col * 68 + 64] = s4;
        };

        #pragma unroll
        for (int i = 0; i < 4; ++i) rel_do(17 - tt + i, rel_ld(17 - tt + i));
        uint4 ru0 = rel_ld(21 - tt), ru1 = rel_ld(22 - tt);

        float4v accPV = zero4;
        float4v accS  = zero4;
        const int mbb = 4 * quad - t0 - col + (TT - 1);

        #pragma unroll 1
        for (int c = 0; c < 9; ++c) {       // chunks of 2 s-tiles: s 0..287
            U8 kf0, kf1;
            if (quad < 2) {
                const uint4 u0 = *(const uint4*)&kp[(2 * c * 32 + quad * 16 + col) * 4];
                const uint4 u1 = *(const uint4*)&kp[((2 * c + 1) * 32 + quad * 16 + col) * 4];
                kf0.w[0] = u0.x; kf0.w[1] = u0.y; kf0.w[2] = u0.z; kf0.w[3] = u0.w;
                kf1.w[0] = u1.x; kf1.w[1] = u1.y; kf1.w[2] = u1.z; kf1.w[3] = u1.w;
            } else {
                kf0.w[0] = kf0.w[1] = kf0.w[2] = kf0.w[3] = 0u;
                kf1.w[0] = kf1.w[1] = kf1.w[2] = kf1.w[3] = 0u;
            }
            const short8 vf = *(const short8*)&vp[(c * 64 + lane) * 4];

            const int mb0 = 32 * c + mbb;
            const float* rp0 = &relw[col * 68 + (mb0 & 63)];
            const float* rp1 = &relw[col * 68 + ((mb0 + 16) & 63)];
            const float4v rc0 = { rp0[0], rp0[1], rp0[2], rp0[3] };
            const float4v rc1 = { rp1[0], rp1[1], rp1[2], rp1[3] };
            const float4v qk0 = __builtin_amdgcn_mfma_f32_16x16x32_bf16(kf0.v, qf.v, rc0, 0, 0, 0);
            const float4v qk1 = __builtin_amdgcn_mfma_f32_16x16x32_bf16(kf1.v, qf.v, rc1, 0, 0, 0);

            const float e0 = ex2(qk0[0]);
            const float e1 = ex2(qk0[1]);
            const float e2 = ex2(qk0[2]);
            const float e3 = ex2(qk0[3]);
            const float e4 = ex2(qk1[0]);
            const float e5 = ex2(qk1[1]);
            const float e6 = ex2(qk1[2]);
            const float e7 = ex2(qk1[3]);

            U8 pf;
            pf.w[0] = pk2(e0, e1);
            pf.w[1] = pk2(e2, e3);
            pf.w[2] = pk2(e4, e5);
            pf.w[3] = pk2(e6, e7);
            accPV = __builtin_amdgcn_mfma_f32_16x16x32_bf16(pf.v, vf, accPV, 0, 0, 0);
            accS  = __builtin_amdgcn_mfma_f32_16x16x32_bf16(pf.v, onef.v, accS, 0, 0, 0);

            rel_do(2 * c + 21 - tt, ru0);
            rel_do(2 * c + 22 - tt, ru1);
            if (c < 8) { ru0 = rel_ld(2 * c + 23 - tt); ru1 = rel_ld(2 * c + 24 - tt); }
        }

        // ---- tail chunk 9: stile 18 only (s 288..303; s>=300 zeroed) ----
        {
            U8 kf0;
            if (quad < 2) {
                const uint4 u0 = *(const uint4*)&kp[(18 * 32 + quad * 16 + col) * 4];
                kf0.w[0] = u0.x; kf0.w[1] = u0.y; kf0.w[2] = u0.z; kf0.w[3] = u0.w;
            } else {
                kf0.w[0] = kf0.w[1] = kf0.w[2] = kf0.w[3] = 0u;
            }
            const int mb0 = 288 + mbb;
            const float* rp0 = &relw[col * 68 + (mb0 & 63)];
            const float4v rc0 = { rp0[0], rp0[1], rp0[2], rp0[3] };
            const float4v qk0 = __builtin_amdgcn_mfma_f32_16x16x32_bf16(kf0.v, qf.v, rc0, 0, 0, 0);
            float e0 = ex2(qk0[0]);
            float e1 = ex2(qk0[1]);
            float e2 = ex2(qk0[2]);
            float e3 = ex2(qk0[3]);
            if (quad == 3) { e0 = e1 = e2 = e3 = 0.f; }
            U8 pf;
            pf.w[0] = pk2(e0, e1);
            pf.w[1] = pk2(e2, e3);
            pf.w[2] = 0u;
            pf.w[3] = 0u;
            const uint2 vu = *(const uint2*)&vp[(9 * 64 + lane) * 4];
            U8 vfu; vfu.w[0] = vu.x; vfu.w[1] = vu.y; vfu.w[2] = 0u; vfu.w[3] = 0u;
            accPV = __builtin_amdgcn_mfma_f32_16x16x32_bf16(pf.v, vfu.v, accPV, 0, 0, 0);
            accS  = __builtin_amdgcn_mfma_f32_16x16x32_bf16(pf.v, onef.v, accS, 0, 0, 0);
        }

        // ---- finalize: accS holds per-lane row sums (t = 4*quad+r) ----
        if (t0 + 4 * quad + 3 < TT) {
            uint2 u;
            u.x = pk2(accPV[0] * rcpf_(accS[0]), accPV[1] * rcpf_(accS[1]));
            u.y = pk2(accPV[2] * rcpf_(accS[2]), accPV[3] * rcpf_(accS[3]));
            *(uint2*)&ah_p[(size_t)(b * 64 + h * 16 + col) * 152 + 8 * tt + 2 * quad] = u;
        }
    }
}

// ---------------------------------------------------------------------------
// k_out (MFMA): per (t-tile, n, t-quarter), 512 thr (waves = otile x t-half).
// x and out through LDS flat buffers (float4-coalesced global traffic).
// ---------------------------------------------------------------------------
__global__ __launch_bounds__(512) void k_out(
        const float* __restrict__ x, const unsigned* __restrict__ W,
        float* __restrict__ out)
{
    const int tt = blockIdx.x, n = blockIdx.y, tq = blockIdx.z;
    if (tt == 18 && tq == 3) return;
    const int t0q = tt * 16 + tq * 4;
    const int tid = threadIdx.x;
    const unsigned* ah_p = W + WS_AH;
    const unsigned* awfrag = W + WS_AWF;
    const float* aoff = (const float*)(W + WS_AOFF);
    const float* scO  = (const float*)(W + WS_SCO);

    __shared__ unsigned fbuf[4 * 1024];    // 16 KB (ah A-frags)
    __shared__ float obuf[6400];           // 25.6 KB (x tile, then out tile)

    // stage x tile (64 o x 4 t x 25 v) via flat float4 (fully coalesced)
    for (int j = tid; j < 1600; j += 512) {
        const int o = j / 25, f4 = j - 25 * o;
        const float4 xv = *(const float4*)(x + (size_t)(n * 64 + o) * 7500 + t0q * 25 + f4 * 4);
        *(float4*)&obuf[o * 100 + f4 * 4] = xv;
    }
    // stage ah A-frags
    for (int i = tid; i < 1600; i += 512) {
        const int tp2 = i & 1, pc = (i >> 1) & 31, v = i >> 6;
        const int b = n * 25 + v;
        const size_t r0 = (size_t)(b * 64 + 2 * pc) * 152 + tt * 8 + tq * 2 + tp2;
        const unsigned A = ah_p[r0], Bv = ah_p[r0 + 152];
        const unsigned ue = (A & 0xFFFFu) | (Bv << 16);
        const unsigned uo = (A >> 16) | (Bv & 0xFFFF0000u);
        const int vt = v >> 4, cv = v & 15, ch = pc >> 4, qd = (pc >> 2) & 3, j2 = pc & 3;
        const int xi = (vt * 2 + ch) * 256 + (qd * 16 + (cv ^ qd)) * 4 + j2;
        const int tl = 2 * tp2;
        fbuf[tl * 1024 + ((xi + 12 * tl) & 1023)]             = ue;
        fbuf[(tl + 1) * 1024 + ((xi + 12 * (tl + 1)) & 1023)] = uo;
    }
    __syncthreads();

    const int wv = tid >> 6, lane = tid & 63, col = lane & 15, quad = lane >> 4;
    const int ow = wv & 3, th = wv >> 2;
    const int o = ow * 16 + col;
    const float4v zero4 = {0.f, 0.f, 0.f, 0.f};

    U8 awf0, awf1;
    { const uint4 u = *(const uint4*)&awfrag[(ow * 2 + 0) * 256 + lane * 4];
      awf0.w[0] = u.x; awf0.w[1] = u.y; awf0.w[2] = u.z; awf0.w[3] = u.w; }
    { const uint4 u = *(const uint4*)&awfrag[(ow * 2 + 1) * 256 + lane * 4];
      awf1.w[0] = u.x; awf1.w[1] = u.y; awf1.w[2] = u.z; awf1.w[3] = u.w; }
    const float aoff_l = aoff[o], sc_l = scO[o];

    for (int tl = 2 * th; tl < 2 * th + 2; ++tl) {
        #pragma unroll
        for (int vt = 0; vt < 2; ++vt) {
            U8 a0, a1;
            { const int xb = (vt * 2 + 0) * 256 + (quad * 16 + (col ^ quad)) * 4;
              const uint4 u = *(const uint4*)&fbuf[tl * 1024 + ((xb + 12 * tl) & 1023)];
              a0.w[0] = u.x; a0.w[1] = u.y; a0.w[2] = u.z; a0.w[3] = u.w; }
            { const int xb = (vt * 2 + 1) * 256 + (quad * 16 + (col ^ quad)) * 4;
              const uint4 u = *(const uint4*)&fbuf[tl * 1024 + ((xb + 12 * tl) & 1023)];
              a1.w[0] = u.x; a1.w[1] = u.y; a1.w[2] = u.z; a1.w[3] = u.w; }
            float4v acc = __builtin_amdgcn_mfma_f32_16x16x32_bf16(a0.v, awf0.v, zero4, 0, 0, 0);
            acc = __builtin_amdgcn_mfma_f32_16x16x32_bf16(a1.v, awf1.v, acc, 0, 0, 0);
            #pragma unroll
            for (int r = 0; r < 4; ++r) {
                const int v = vt * 16 + 4 * quad + r;
                if (v < 25) {
                    const int oi = o * 100 + tl * 25 + v;
                    obuf[oi] = fmaxf(fmaf(obuf[oi], sc_l, acc[r] + aoff_l), 0.f);
                }
            }
        }
    }
    __syncthreads();

    // flush out tile via flat float4 (fully coalesced)
    for (int j = tid; j < 1600; j += 512) {
        const int o2 = j / 25, f4 = j - 25 * o2;
        *(float4*)(out + (size_t)(n * 64 + o2) * 7500 + t0q * 25 + f4 * 4) =
            *(const float4*)&obuf[o2 * 100 + f4 * 4];
    }
}

// ---------------------------------------------------------------------------
extern "C" void kernel_launch(void* const* d_in, const int* in_sizes, int n_in,
                              void* d_out, int out_size, void* d_ws, size_t ws_size,
                              hipStream_t stream)
{
    const float* x       = (const float*)d_in[0];
    const float* dbn_g   = (const float*)d_in[1];
    const float* dbn_b   = (const float*)d_in[2];
    const float* dbn_m   = (const float*)d_in[3];
    const float* dbn_v   = (const float*)d_in[4];
    const float* qkv_w   = (const float*)d_in[5];
    const float* qkv_b   = (const float*)d_in[6];
    const float* key_rel = (const float*)d_in[7];
    const float* attn_w  = (const float*)d_in[8];
    const float* attn_b  = (const float*)d_in[9];
    const float* bn_g    = (const float*)d_in[10];
    const float* bn_b    = (const float*)d_in[11];
    const float* bn_m    = (const float*)d_in[12];
    const float* bn_v    = (const float*)d_in[13];
    float* out = (float*)d_out;
    unsigned* W = (unsigned*)d_ws;

    k_pre<<<26, 256, 0, stream>>>(dbn_g, dbn_b, dbn_m, dbn_v, qkv_w, qkv_b,
                                  key_rel, attn_w, attn_b, bn_g, bn_b, bn_m,
                                  bn_v, W);
    k_qkv<<<dim3(19, 16), 512, 0, stream>>>(x, W);
    k_attn<<<1600, 512, 0, stream>>>(W);
    k_out<<<dim3(19, 16, 4), 512, 0, stream>>>(x, W, out);
}

// Round 4
// 233.785 us; speedup vs baseline: 1.1700x; 1.1035x over previous
//
#include <hip/hip_runtime.h>
#include <hip/hip_bf16.h>
#include <cstddef>

// Problem constants
#define NN 16
#define CC 64
#define TT 300
#define VV 25
#define NHH 4
#define DKHH 16
#define BB (NN * VV)          // 400
#define EPS 1e-5f
#define LOG2E 1.4426950408889634f

// Workspace layout (u32 units)
#define WS_QK    0            // u32[400][64][300]  q|k bf16, paired along o (q pre-scaled 0.25*log2e)
#define WS_V     7680000      // u32[400][64][152]  v bf16, paired along t (t>=300 zero-filled)
#define WS_AH    11571200     // u32[400][64][152]  attnh bf16, paired along t
#define WS_REL   15462400     // u32[41][64][4] key_rel frags (slot = mtile+1, slot0 = zeros)
#define WS_AWF   15472896     // u32[4][2][64][4] attn_w B-frags (pre-scaled by bn scale)
#define WS_AOFF  15474944     // f32[64] fused attn_b+bn offset
#define WS_SCO   15475008     // f32[64] bn scale (for skip path)
#define WS_WFRAG 15475072     // u32[12][2][64][4] qkv_w B-frags (q pre-scaled 0.25*log2e)
#define WS_QB2   15481216     // f32[192] qkv_b (q pre-scaled)
#define WS_SCSH  15481408     // float2[1600] data_bn (sc, sh) per (c, v)

typedef __attribute__((ext_vector_type(8))) short short8;
typedef __attribute__((ext_vector_type(4))) float float4v;

union U8 { short8 v; unsigned int w[4]; };

// f32x2 -> packed bf16x2 (RNE). HW op if available, else manual.
__device__ __forceinline__ unsigned int pk2(float a, float b) {
#if __has_builtin(__builtin_amdgcn_cvt_pk_bf16_f32)
    typedef __attribute__((ext_vector_type(2))) __bf16 bf2;
    union { bf2 v; unsigned u; } c;
    c.v = __builtin_amdgcn_cvt_pk_bf16_f32(a, b);
    return c.u;
#else
    union { float f; unsigned u; } x, y;
    x.f = a; y.f = b;
    unsigned ua = x.u + 0x7FFFu + ((x.u >> 16) & 1u);
    unsigned ub = y.u + 0x7FFFu + ((y.u >> 16) & 1u);
    return (ua >> 16) | (ub & 0xFFFF0000u);
#endif
}

__device__ __forceinline__ float ex2(float x) {
#if __has_builtin(__builtin_amdgcn_exp2f)
    return __builtin_amdgcn_exp2f(x);
#else
    return exp2f(x);
#endif
}

__device__ __forceinline__ float rcpf_(float x) {
#if __has_builtin(__builtin_amdgcn_rcpf)
    return __builtin_amdgcn_rcpf(x);
#else
    return 1.f / x;
#endif
}

// ---------------------------------------------------------------------------
// k_pre: constant tables.
// ---------------------------------------------------------------------------
__global__ __launch_bounds__(256) void k_pre(
    const float* __restrict__ dbn_g, const float* __restrict__ dbn_b,
    const float* __restrict__ dbn_m, const float* __restrict__ dbn_v,
    const float* __restrict__ qkv_w, const float* __restrict__ qkv_b,
    const float* __restrict__ key_rel,
    const float* __restrict__ attn_w, const float* __restrict__ attn_b,
    const float* __restrict__ bn_g, const float* __restrict__ bn_b,
    const float* __restrict__ bn_m, const float* __restrict__ bn_v,
    unsigned* __restrict__ W)
{
    const int jid = blockIdx.x * 256 + threadIdx.x;
    if (jid < 2624) {                      // relfrag: 41 slots x 64 lanes
        const int k = jid >> 6, lane = jid & 63, col = lane & 15, quad = lane >> 4;
        const int mt = k - 1, m = mt * 16 + col;
        const bool ok = (quad < 2) && (mt >= 0) && (m < 2 * TT - 1);
        unsigned w[4];
        #pragma unroll
        for (int j2 = 0; j2 < 4; ++j2) {
            const int c = quad * 8 + 2 * j2;
            const float v0 = ok ? key_rel[m * 16 + c] : 0.f;
            const float v1 = ok ? key_rel[m * 16 + c + 1] : 0.f;
            w[j2] = pk2(v0, v1);
        }
        *(uint4*)&W[WS_REL + k * 256 + lane * 4] = make_uint4(w[0], w[1], w[2], w[3]);
    } else if (jid < 3136) {               // awfrag: 4 otiles x 2 chalf x 64
        const int e = jid - 2624;
        const int ot = e >> 7, ch = (e >> 6) & 1, lane = e & 63;
        const int col = lane & 15, quad = lane >> 4;
        const int o = ot * 16 + col;
        const float sc = bn_g[o] * rsqrtf(bn_v[o] + EPS);
        unsigned w[4];
        #pragma unroll
        for (int j2 = 0; j2 < 4; ++j2) {
            const int c = ch * 32 + quad * 8 + 2 * j2;
            w[j2] = pk2(attn_w[o * 64 + c] * sc, attn_w[o * 64 + c + 1] * sc);
        }
        *(uint4*)&W[WS_AWF + (ot * 2 + ch) * 256 + lane * 4] = make_uint4(w[0], w[1], w[2], w[3]);
    } else if (jid < 3200) {               // aoff
        const int o = jid - 3136;
        const float sc = bn_g[o] * rsqrtf(bn_v[o] + EPS);
        ((float*)(W + WS_AOFF))[o] = attn_b[o] * sc + bn_b[o] - bn_m[o] * sc;
    } else if (jid < 3264) {               // scO
        const int o = jid - 3200;
        ((float*)(W + WS_SCO))[o] = bn_g[o] * rsqrtf(bn_v[o] + EPS);
    } else if (jid < 4800) {               // wfrag: 12 otiles x 2 chalf x 64
        const int e = jid - 3264;
        const int ot = e >> 7, ch = (e >> 6) & 1, lane = e & 63;
        const int col = lane & 15, quad = lane >> 4;
        const int o = ot * 16 + col;
        const float qs = (o < 64) ? 0.25f * LOG2E : 1.f;
        unsigned w[4];
        #pragma unroll
        for (int j2 = 0; j2 < 4; ++j2) {
            const int c = ch * 32 + quad * 8 + 2 * j2;
            w[j2] = pk2(qkv_w[o * 64 + c] * qs, qkv_w[o * 64 + c + 1] * qs);
        }
        *(uint4*)&W[WS_WFRAG + (ot * 2 + ch) * 256 + lane * 4] = make_uint4(w[0], w[1], w[2], w[3]);
    } else if (jid < 4992) {               // qb2
        const int o = jid - 4800;
        ((float*)(W + WS_QB2))[o] = qkv_b[o] * ((o < 64) ? 0.25f * LOG2E : 1.f);
    } else if (jid < 6592) {               // data_bn sc/sh per (c*25+v)
        const int e = jid - 4992;
        const float sc = dbn_g[e] * rsqrtf(dbn_v[e] + EPS);
        const float sh = dbn_b[e] - dbn_m[e] * sc;
        ((float2*)(W + WS_SCSH))[e] = make_float2(sc, sh);
    }
}

// ---------------------------------------------------------------------------
// k_qkv (MFMA): per (t-tile, n), 512 thr. float4 coalesced x loads, data_bn
// applied in staging (scsh fmaf from LDS table); shared weight B-frags loaded
// ONCE per wave.
// ---------------------------------------------------------------------------
__global__ __launch_bounds__(512) void k_qkv(
        const float* __restrict__ x, unsigned* __restrict__ W)
{
    const int tt = blockIdx.x, n = blockIdx.y, t0 = tt * 16;
    const int tid = threadIdx.x;
    const unsigned* wfrag = W + WS_WFRAG;
    const float* qb2 = (const float*)(W + WS_QB2);
    unsigned* qk_p = W + WS_QK;
    unsigned* v_p  = W + WS_V;

    __shared__ unsigned afrag[25 * 516];   // 51.6 KB
    __shared__ float2 sls[1600];           // 12.8 KB data_bn (sc,sh) table

    for (int i = tid; i < 1600; i += 512)
        sls[i] = ((const float2*)(W + WS_SCSH))[i];
    __syncthreads();

    // stage: 3200 jobs = 32 c-pairs x 100 float4 (contiguous flat = t*25+v)
    for (int i = tid; i < 3200; i += 512) {
        const int f4 = i % 100, cp = i / 100;
        const int c0 = cp * 2;
        float4 xa = make_float4(0.f, 0.f, 0.f, 0.f);
        float4 xb = make_float4(0.f, 0.f, 0.f, 0.f);
        if (tt < 18 || f4 < 75) {          // tail tile: only 300 floats valid
            const float* p = x + (size_t)(n * 64 + c0) * 7500 + tt * 400 + f4 * 4;
            xa = *(const float4*)p;
            xb = *(const float4*)(p + 7500);
        }
        const int ch = cp >> 4, qd = (cp >> 2) & 3, j2 = cp & 3;
        const float ea[4] = {xa.x, xa.y, xa.z, xa.w};
        const float eb[4] = {xb.x, xb.y, xb.z, xb.w};
        #pragma unroll
        for (int e = 0; e < 4; ++e) {
            const int flat = f4 * 4 + e;
            const int tl = (flat * 5243) >> 17;     // flat / 25
            const int v  = flat - 25 * tl;
            const float2 s0 = sls[c0 * 25 + v];
            const float2 s1 = sls[c0 * 25 + 25 + v];
            const float a0 = fmaf(ea[e], s0.x, s0.y);
            const float a1 = fmaf(eb[e], s1.x, s1.y);
            afrag[v * 516 + (ch * 64 + qd * 16 + tl) * 4 + j2] = pk2(a0, a1);
        }
    }
    __syncthreads();

    const int wvv = tid >> 6, lane = tid & 63, col = lane & 15, quad = lane >> 4;
    const int otg = wvv >> 1, vh = wvv & 1;
    const int vlo = 13 * vh, vhi = vh ? 25 : 13;
    const float4v zero4 = {0.f, 0.f, 0.f, 0.f};
    const bool tvalid = (t0 + 4 * quad + 3 < TT);

    U8 bf[3][2]; float qb_l[3];
    #pragma unroll
    for (int i = 0; i < 3; ++i) {
        const int ot = 3 * otg + i;
        #pragma unroll
        for (int ch = 0; ch < 2; ++ch) {
            const uint4 u = *(const uint4*)&wfrag[(ot * 2 + ch) * 256 + lane * 4];
            bf[i][ch].w[0] = u.x; bf[i][ch].w[1] = u.y; bf[i][ch].w[2] = u.z; bf[i][ch].w[3] = u.w;
        }
        qb_l[i] = qb2[ot * 16 + col];
    }

    for (int v = vlo; v < vhi; ++v) {
        const int b = n * 25 + v;
        U8 a0, a1;
        { const uint4 u = *(const uint4*)&afrag[v * 516 + lane * 4];
          a0.w[0] = u.x; a0.w[1] = u.y; a0.w[2] = u.z; a0.w[3] = u.w; }
        { const uint4 u = *(const uint4*)&afrag[v * 516 + 256 + lane * 4];
          a1.w[0] = u.x; a1.w[1] = u.y; a1.w[2] = u.z; a1.w[3] = u.w; }
        #pragma unroll
        for (int i = 0; i < 3; ++i) {
            const int ot = 3 * otg + i;
            float4v acc = __builtin_amdgcn_mfma_f32_16x16x32_bf16(a0.v, bf[i][0].v, zero4, 0, 0, 0);
            acc = __builtin_amdgcn_mfma_f32_16x16x32_bf16(a1.v, bf[i][1].v, acc, 0, 0, 0);
            float val[4];
            #pragma unroll
            for (int r = 0; r < 4; ++r) val[r] = acc[r] + qb_l[i];
            if (ot < 8) {                  // q|k: pair neighbor o lanes
                unsigned pk[4];
                #pragma unroll
                for (int r = 0; r < 4; ++r) {
                    const float p = __shfl_xor(val[r], 1);
                    pk[r] = pk2(val[r], p);
                }
                if (((col & 1) == 0) && tvalid) {
                    const int op = ot * 8 + (col >> 1);
                    *(uint4*)&qk_p[(size_t)(b * 64 + op) * TT + t0 + 4 * quad] =
                        make_uint4(pk[0], pk[1], pk[2], pk[3]);
                }
            } else {                       // v: pair along t; zero-fill t>=300
                const int d = (ot - 8) * 16 + col;
                uint2 u;
                if (tvalid) { u.x = pk2(val[0], val[1]); u.y = pk2(val[2], val[3]); }
                else        { u.x = 0u; u.y = 0u; }
                *(uint2*)&v_p[(size_t)(b * 64 + d) * 152 + 8 * tt + 2 * quad] = u;
            }
        }
    }
}

// ---------------------------------------------------------------------------
// k_attn: per (b, h, t-half). R1 structure (LDS kbuf/vbuf) + s-indexed rel
// ring: critical-path ring reads are ALIGNED ds_read_b128 (col-independent
// offset (32c+4q)&63); the col-dependent misalignment lives on the fire-and-
// forget rel_do writes (4x masked b32). Chunk loop unrolled 3x so the
// scheduler can pipeline chunk c+1's LDS reads / QK MFMAs under chunk c's
// exp2/pk2/PV (registers are free: VGPR cap 128 via launch_bounds).
// ---------------------------------------------------------------------------
__global__ __launch_bounds__(256, 4) void k_attn(unsigned* __restrict__ W)
{
    const int bh = blockIdx.x;             // 0..1599
    const int half = blockIdx.y;           // t-range half
    const int b = bh >> 2, h = bh & 3;
    const int tid  = threadIdx.x;
    const int wave = tid >> 6, lane = tid & 63;
    const int col  = lane & 15, quad = lane >> 4;

    const unsigned* qk_p = W + WS_QK;
    const unsigned* v_p  = W + WS_V;
    unsigned* ah_p = W + WS_AH;
    const unsigned* relfrag = W + WS_REL;

    __shared__ unsigned kbuf[19 * 32 * 4];   // 9.7 KB
    __shared__ unsigned vbuf[10 * 64 * 4];   // 10.2 KB (s-permuted)
    __shared__ float relbuf[4][16 * 68];     // per-wave s-ring (64 slots + pad)

    for (int p = tid; p < 2432; p += 256) {
        const int c = p & 15, j2 = (p >> 4) & 3, qh = (p >> 6) & 1, st = p >> 7;
        kbuf[(st * 32 + qh * 16 + c) * 4 + j2] =
            qk_p[(size_t)(b * 64 + 32 + h * 8 + qh * 4 + j2) * TT + st * 16 + c];
    }
    // V staging with k<->s permutation: quad q of the PV A/B frag owns
    // s-pairs {2q, 2q+1, 8+2q, 8+2q+1} within each 32-s chunk.
    for (int p = tid; p < 640; p += 256) {
        const int tq = p % 40, d = p / 40;
        const int off = (tq * 4 <= 148) ? tq * 4 : 144;  // clamp (slots unused)
        const uint4 u = *(const uint4*)&v_p[(size_t)(b * 64 + h * 16 + d) * 152 + off];
        const int c = tq >> 2;
        const int l0 = (tq & 3) * 4;
        const unsigned uu[4] = {u.x, u.y, u.z, u.w};
        #pragma unroll
        for (int j = 0; j < 4; ++j) {
            const int local = l0 + j;
            const int q  = (local < 8) ? (local >> 1) : ((local - 8) >> 1);
            const int j2 = (local < 8) ? (local & 1) : (2 + (local & 1));
            vbuf[(c * 64 + q * 16 + d) * 4 + j2] = uu[j];
        }
    }
    __syncthreads();

    float* relw = &relbuf[wave][0];
    const float4v zero4 = {0.f, 0.f, 0.f, 0.f};
    U8 onef;
    onef.w[0] = onef.w[1] = onef.w[2] = onef.w[3] = 0x3F803F80u;

    const int ttlo = half ? 10 : 0;
    const int tthi = half ? 19 : 10;

    for (int tt = ttlo + wave; tt < tthi; tt += 4) {
        const int t0 = tt * 16;

        // ---- Q B-frag (cols = t) ----
        U8 qf;
        if (quad < 2) {
            int t = t0 + col; if (t > TT - 1) t = TT - 1;
            const size_t rb = (size_t)(b * 64 + h * 8 + quad * 4) * TT + t;
            qf.w[0] = qk_p[rb];
            qf.w[1] = qk_p[rb + TT];
            qf.w[2] = qk_p[rb + 2 * TT];
            qf.w[3] = qk_p[rb + 3 * TT];
        } else {
            qf.w[0] = qf.w[1] = qf.w[2] = qf.w[3] = 0u;
        }

        auto rel_ld = [&](int mt) -> uint4 {
            return *(const uint4*)&relfrag[(mt + 1) * 256 + lane * 4];
        };
        // s-ring write: slot(s) = (m + t - 299) mod 64, s = diag index.
        // lane holds R[m = mt*16+4q+r, t = t0+col]; -299 == +21 (mod 64).
        auto rel_do = [&](int mt, uint4 u) {
            U8 kr; kr.w[0] = u.x; kr.w[1] = u.y; kr.w[2] = u.z; kr.w[3] = u.w;
            const float4v rc = __builtin_amdgcn_mfma_f32_16x16x32_bf16(
                                   kr.v, qf.v, zero4, 0, 0, 0);
            const int wbase = mt * 16 + 4 * quad + t0 + col + 21;
            float* rw = &relw[col * 68];
            rw[wbase & 63]       = rc[0];
            rw[(wbase + 1) & 63] = rc[1];
            rw[(wbase + 2) & 63] = rc[2];
            rw[(wbase + 3) & 63] = rc[3];
        };

        #pragma unroll
        for (int i = 0; i < 4; ++i) rel_do(17 - tt + i, rel_ld(17 - tt + i));
        uint4 ru0 = rel_ld(21 - tt), ru1 = rel_ld(22 - tt);

        float4v accPV = zero4;
        float4v accS  = zero4;

        #pragma unroll 3
        for (int c = 0; c < 9; ++c) {       // chunks of 2 s-tiles: s 0..287
            U8 kf0, kf1;
            if (quad < 2) {
                const uint4 u0 = *(const uint4*)&kbuf[((2 * c) * 32 + quad * 16 + col) * 4];
                const uint4 u1 = *(const uint4*)&kbuf[((2 * c + 1) * 32 + quad * 16 + col) * 4];
                kf0.w[0] = u0.x; kf0.w[1] = u0.y; kf0.w[2] = u0.z; kf0.w[3] = u0.w;
                kf1.w[0] = u1.x; kf1.w[1] = u1.y; kf1.w[2] = u1.z; kf1.w[3] = u1.w;
            } else {
                kf0.w[0] = kf0.w[1] = kf0.w[2] = kf0.w[3] = 0u;
                kf1.w[0] = kf1.w[1] = kf1.w[2] = kf1.w[3] = 0u;
            }
            const short8 vf = *(const short8*)&vbuf[(c * 64 + lane) * 4];

            // aligned s-ring reads: rows s = 32c+4q+r (qk0), +16 (qk1)
            const int rb0 = (32 * c + 4 * quad) & 63;
            const float4v rc0 = *(const float4v*)&relw[col * 68 + rb0];
            const float4v rc1 = *(const float4v*)&relw[col * 68 + ((rb0 + 16) & 63)];
            const float4v qk0 = __builtin_amdgcn_mfma_f32_16x16x32_bf16(kf0.v, qf.v, rc0, 0, 0, 0);
            const float4v qk1 = __builtin_amdgcn_mfma_f32_16x16x32_bf16(kf1.v, qf.v, rc1, 0, 0, 0);

            const float e0 = ex2(qk0[0]);
            const float e1 = ex2(qk0[1]);
            const float e2 = ex2(qk0[2]);
            const float e3 = ex2(qk0[3]);
            const float e4 = ex2(qk1[0]);
            const float e5 = ex2(qk1[1]);
            const float e6 = ex2(qk1[2]);
            const float e7 = ex2(qk1[3]);

            U8 pf;
            pf.w[0] = pk2(e0, e1);
            pf.w[1] = pk2(e2, e3);
            pf.w[2] = pk2(e4, e5);
            pf.w[3] = pk2(e6, e7);
            accPV = __builtin_amdgcn_mfma_f32_16x16x32_bf16(pf.v, vf, accPV, 0, 0, 0);
            accS  = __builtin_amdgcn_mfma_f32_16x16x32_bf16(pf.v, onef.v, accS, 0, 0, 0);

            rel_do(2 * c + 21 - tt, ru0);
            rel_do(2 * c + 22 - tt, ru1);
            if (c < 8) { ru0 = rel_ld(2 * c + 23 - tt); ru1 = rel_ld(2 * c + 24 - tt); }
        }

        // ---- tail chunk 9: stile 18 only (s 288..303; s>=300 masked) ----
        {
            U8 kf0;
            if (quad < 2) {
                const uint4 u0 = *(const uint4*)&kbuf[(18 * 32 + quad * 16 + col) * 4];
                kf0.w[0] = u0.x; kf0.w[1] = u0.y; kf0.w[2] = u0.z; kf0.w[3] = u0.w;
            } else {
                kf0.w[0] = kf0.w[1] = kf0.w[2] = kf0.w[3] = 0u;
            }
            const int rb0 = (288 + 4 * quad) & 63;
            const float4v rc0 = *(const float4v*)&relw[col * 68 + rb0];
            const float4v qk0 = __builtin_amdgcn_mfma_f32_16x16x32_bf16(kf0.v, qf.v, rc0, 0, 0, 0);
            float e0 = ex2(qk0[0]);
            float e1 = ex2(qk0[1]);
            float e2 = ex2(qk0[2]);
            float e3 = ex2(qk0[3]);
            if (quad == 3) { e0 = e1 = e2 = e3 = 0.f; }
            U8 pf;
            pf.w[0] = pk2(e0, e1);
            pf.w[1] = pk2(e2, e3);
            pf.w[2] = 0u;
            pf.w[3] = 0u;
            const short8 vf = *(const short8*)&vbuf[(9 * 64 + lane) * 4];
            accPV = __builtin_amdgcn_mfma_f32_16x16x32_bf16(pf.v, vf, accPV, 0, 0, 0);
            accS  = __builtin_amdgcn_mfma_f32_16x16x32_bf16(pf.v, onef.v, accS, 0, 0, 0);
        }

        // ---- finalize: accS holds per-lane row sums (t = 4*quad+r) ----
        if (t0 + 4 * quad + 3 < TT) {
            uint2 u;
            u.x = pk2(accPV[0] * rcpf_(accS[0]), accPV[1] * rcpf_(accS[1]));
            u.y = pk2(accPV[2] * rcpf_(accS[2]), accPV[3] * rcpf_(accS[3]));
            *(uint2*)&ah_p[(size_t)(b * 64 + h * 16 + col) * 152 + 8 * tt + 2 * quad] = u;
        }
    }
}

// ---------------------------------------------------------------------------
// k_out (MFMA): per (t-tile, n, t-quarter), 512 thr (waves = otile x t-half).
// x and out through LDS flat buffers (float4-coalesced global traffic).
// ---------------------------------------------------------------------------
__global__ __launch_bounds__(512) void k_out(
        const float* __restrict__ x, const unsigned* __restrict__ W,
        float* __restrict__ out)
{
    const int tt = blockIdx.x, n = blockIdx.y, tq = blockIdx.z;
    if (tt == 18 && tq == 3) return;
    const int t0q = tt * 16 + tq * 4;
    const int tid = threadIdx.x;
    const unsigned* ah_p = W + WS_AH;
    const unsigned* awfrag = W + WS_AWF;
    const float* aoff = (const float*)(W + WS_AOFF);
    const float* scO  = (const float*)(W + WS_SCO);

    __shared__ unsigned fbuf[4 * 1024];    // 16 KB (ah A-frags)
    __shared__ float obuf[6400];           // 25.6 KB (x tile, then out tile)

    // stage x tile (64 o x 4 t x 25 v) via flat float4 (fully coalesced)
    for (int j = tid; j < 1600; j += 512) {
        const int o = j / 25, f4 = j - 25 * o;
        const float4 xv = *(const float4*)(x + (size_t)(n * 64 + o) * 7500 + t0q * 25 + f4 * 4);
        *(float4*)&obuf[o * 100 + f4 * 4] = xv;
    }
    // stage ah A-frags
    for (int i = tid; i < 1600; i += 512) {
        const int tp2 = i & 1, pc = (i >> 1) & 31, v = i >> 6;
        const int b = n * 25 + v;
        const size_t r0 = (size_t)(b * 64 + 2 * pc) * 152 + tt * 8 + tq * 2 + tp2;
        const unsigned A = ah_p[r0], Bv = ah_p[r0 + 152];
        const unsigned ue = (A & 0xFFFFu) | (Bv << 16);
        const unsigned uo = (A >> 16) | (Bv & 0xFFFF0000u);
        const int vt = v >> 4, cv = v & 15, ch = pc >> 4, qd = (pc >> 2) & 3, j2 = pc & 3;
        const int xi = (vt * 2 + ch) * 256 + (qd * 16 + (cv ^ qd)) * 4 + j2;
        const int tl = 2 * tp2;
        fbuf[tl * 1024 + ((xi + 12 * tl) & 1023)]             = ue;
        fbuf[(tl + 1) * 1024 + ((xi + 12 * (tl + 1)) & 1023)] = uo;
    }
    __syncthreads();

    const int wv = tid >> 6, lane = tid & 63, col = lane & 15, quad = lane >> 4;
    const int ow = wv & 3, th = wv >> 2;
    const int o = ow * 16 + col;
    const float4v zero4 = {0.f, 0.f, 0.f, 0.f};

    U8 awf0, awf1;
    { const uint4 u = *(const uint4*)&awfrag[(ow * 2 + 0) * 256 + lane * 4];
      awf0.w[0] = u.x; awf0.w[1] = u.y; awf0.w[2] = u.z; awf0.w[3] = u.w; }
    { const uint4 u = *(const uint4*)&awfrag[(ow * 2 + 1) * 256 + lane * 4];
      awf1.w[0] = u.x; awf1.w[1] = u.y; awf1.w[2] = u.z; awf1.w[3] = u.w; }
    const float aoff_l = aoff[o], sc_l = scO[o];

    for (int tl = 2 * th; tl < 2 * th + 2; ++tl) {
        #pragma unroll
        for (int vt = 0; vt < 2; ++vt) {
            U8 a0, a1;
            { const int xb = (vt * 2 + 0) * 256 + (quad * 16 + (col ^ quad)) * 4;
              const uint4 u = *(const uint4*)&fbuf[tl * 1024 + ((xb + 12 * tl) & 1023)];
              a0.w[0] = u.x; a0.w[1] = u.y; a0.w[2] = u.z; a0.w[3] = u.w; }
            { const int xb = (vt * 2 + 1) * 256 + (quad * 16 + (col ^ quad)) * 4;
              const uint4 u = *(const uint4*)&fbuf[tl * 1024 + ((xb + 12 * tl) & 1023)];
              a1.w[0] = u.x; a1.w[1] = u.y; a1.w[2] = u.z; a1.w[3] = u.w; }
            float4v acc = __builtin_amdgcn_mfma_f32_16x16x32_bf16(a0.v, awf0.v, zero4, 0, 0, 0);
            acc = __builtin_amdgcn_mfma_f32_16x16x32_bf16(a1.v, awf1.v, acc, 0, 0, 0);
            #pragma unroll
            for (int r = 0; r < 4; ++r) {
                const int v = vt * 16 + 4 * quad + r;
                if (v < 25) {
                    const int oi = o * 100 + tl * 25 + v;
                    obuf[oi] = fmaxf(fmaf(obuf[oi], sc_l, acc[r] + aoff_l), 0.f);
                }
            }
        }
    }
    __syncthreads();

    // flush out tile via flat float4 (fully coalesced)
    for (int j = tid; j < 1600; j += 512) {
        const int o2 = j / 25, f4 = j - 25 * o2;
        *(float4*)(out + (size_t)(n * 64 + o2) * 7500 + t0q * 25 + f4 * 4) =
            *(const float4*)&obuf[o2 * 100 + f4 * 4];
    }
}

// ---------------------------------------------------------------------------
extern "C" void kernel_launch(void* const* d_in, const int* in_sizes, int n_in,
                              void* d_out, int out_size, void* d_ws, size_t ws_size,
                              hipStream_t stream)
{
    const float* x       = (const float*)d_in[0];
    const float* dbn_g   = (const float*)d_in[1];
    const float* dbn_b   = (const float*)d_in[2];
    const float* dbn_m   = (const float*)d_in[3];
    const float* dbn_v   = (const float*)d_in[4];
    const float* qkv_w   = (const float*)d_in[5];
    const float* qkv_b   = (const float*)d_in[6];
    const float* key_rel = (const float*)d_in[7];
    const float* attn_w  = (const float*)d_in[8];
    const float* attn_b  = (const float*)d_in[9];
    const float* bn_g    = (const float*)d_in[10];
    const float* bn_b    = (const float*)d_in[11];
    const float* bn_m    = (const float*)d_in[12];
    const float* bn_v    = (const float*)d_in[13];
    float* out = (float*)d_out;
    unsigned* W = (unsigned*)d_ws;

    k_pre<<<26, 256, 0, stream>>>(dbn_g, dbn_b, dbn_m, dbn_v, qkv_w, qkv_b,
                                  key_rel, attn_w, attn_b, bn_g, bn_b, bn_m,
                                  bn_v, W);
    k_qkv<<<dim3(19, 16), 512, 0, stream>>>(x, W);
    k_attn<<<dim3(1600, 2), 256, 0, stream>>>(W);
    k_out<<<dim3(19, 16, 4), 512, 0, stream>>>(x, W, out);
}